// Round 1
// baseline (63.545 us; speedup 1.0000x reference)
//
#include <hip/hip_runtime.h>
#include <math.h>

#define NC 17
#define PLANE 640000            // 200*200*16
#define NVOX (2 * PLANE)        // B=2
#define BETA_C 0.95f
#define ALPHA_C 5.0f
#define WPC_C 3.0f
#define IGNORE_C 255

// ---------------------------------------------------------------------------
// Kernel 1: per-voxel softmax + per-class partial sums.
// acc layout (3*NC floats): [0..16]=nominator, [17..33]=sum_p, [34..50]=sum_comp
// ---------------------------------------------------------------------------
__global__ __launch_bounds__(256) void al_reduce(const float* __restrict__ pred,
                                                 const int* __restrict__ tgt,
                                                 float* __restrict__ acc) {
    float nom[NC], sump[NC], cnt[NC];
#pragma unroll
    for (int c = 0; c < NC; ++c) { nom[c] = 0.f; sump[c] = 0.f; cnt[c] = 0.f; }

    const int stride = gridDim.x * blockDim.x;
    for (int v = blockIdx.x * blockDim.x + threadIdx.x; v < NVOX; v += stride) {
        const int t = tgt[v];
        if (t == IGNORE_C) continue;                 // mask
        const int b = (v >= PLANE) ? 1 : 0;
        const int n = v - b * PLANE;
        const float* p0 = pred + (size_t)b * ((size_t)NC * PLANE) + n;

        float x[NC];
#pragma unroll
        for (int c = 0; c < NC; ++c) x[c] = p0[(size_t)c * PLANE];

        float mx = x[0];
#pragma unroll
        for (int c = 1; c < NC; ++c) mx = fmaxf(mx, x[c]);

        float s = 0.f;
#pragma unroll
        for (int c = 0; c < NC; ++c) { x[c] = __expf(x[c] - mx); s += x[c]; }
        const float inv = 1.0f / s;

#pragma unroll
        for (int c = 0; c < NC; ++c) {
            const float p = x[c] * inv;
            sump[c] += p;
            const bool ist = (c == t);               // compile-time reg index only
            nom[c] += ist ? p : 0.f;
            cnt[c] += ist ? 1.f : 0.f;
        }
    }

    // wave (64-lane) butterfly reduce of the 51 partials
#pragma unroll
    for (int c = 0; c < NC; ++c) {
#pragma unroll
        for (int off = 32; off > 0; off >>= 1) {
            nom[c]  += __shfl_down(nom[c],  (unsigned)off, 64);
            sump[c] += __shfl_down(sump[c], (unsigned)off, 64);
            cnt[c]  += __shfl_down(cnt[c],  (unsigned)off, 64);
        }
    }

    __shared__ float lds[3 * NC];
    if (threadIdx.x < 3 * NC) lds[threadIdx.x] = 0.f;
    __syncthreads();
    if ((threadIdx.x & 63) == 0) {                   // lane 0 of each of 4 waves
#pragma unroll
        for (int c = 0; c < NC; ++c) {
            atomicAdd(&lds[c],          nom[c]);
            atomicAdd(&lds[NC + c],     sump[c]);
            atomicAdd(&lds[2 * NC + c], cnt[c]);
        }
    }
    __syncthreads();
    if (threadIdx.x < 3 * NC) atomicAdd(&acc[threadIdx.x], lds[threadIdx.x]);
}

// ---------------------------------------------------------------------------
// Kernel 2: O(C) scalar epilogue on one thread.
// ---------------------------------------------------------------------------
__device__ __forceinline__ float bce_ones(float x) {
    // F.binary_cross_entropy(x, ones) = min(-log(max(x,1e-38)), 100)
    return fminf(-logf(fmaxf(x, 1e-38f)), 100.0f);
}

__global__ void al_finalize(const float* __restrict__ acc,
                            const float* __restrict__ f1_list,
                            float* __restrict__ out) {
    if (threadIdx.x != 0 || blockIdx.x != 0) return;

    float nom[NC], sump[NC], cnt[NC];
    float n_mask = 0.f;
    for (int c = 0; c < NC; ++c) {
        nom[c]  = acc[c];
        sump[c] = acc[NC + c];
        cnt[c]  = acc[2 * NC + c];
        n_mask += cnt[c];
    }

    float loss_list[NC], newf1[NC];
    float count = 0.f;
    for (int c = 0; c < NC; ++c) {
        const bool has = cnt[c] > 0.f;
        const float prec = (sump[c] > 0.f) ? nom[c] / sump[c] : 0.f;
        const float rec  = has ? nom[c] / cnt[c] : 0.f;
        const float negc = n_mask - cnt[c];
        const float spec_num = (n_mask - sump[c]) - (cnt[c] - nom[c]);
        const float spec = (negc > 0.f) ? spec_num / negc : 0.f;

        float ll = 0.f;
        if (has) {
            ll  = (sump[c] > 0.f) ? bce_ones(prec) : 0.f;
            ll += bce_ones(rec);
            ll += (negc > 0.f) ? bce_ones(spec) : 0.f;
        }
        loss_list[c] = ll;

        const float den = prec + rec;
        const float f1  = (den > 0.f) ? 2.f * prec * rec / den : 0.f;
        const float cur = has ? f1 : 0.f;
        newf1[c] = BETA_C * f1_list[c] + (1.f - BETA_C) * cur;
        count += has ? 1.f : 0.f;
    }

    const float wp = WPC_C * count;

    float mx = -INFINITY;
    for (int c = 0; c < NC; ++c) {
        const float lg = (loss_list[c] != 0.f) ? ALPHA_C * (1.f - newf1[c]) : -INFINITY;
        mx = fmaxf(mx, lg);
    }
    float e[NC];
    float se = 0.f;
    for (int c = 0; c < NC; ++c) {
        const float lg = (loss_list[c] != 0.f) ? ALPHA_C * (1.f - newf1[c]) : -INFINITY;
        e[c] = expf(lg - mx);     // exp(-inf) = 0 for unselected classes
        se += e[c];
    }

    float total = 0.f;
    for (int c = 0; c < NC; ++c) {
        const float sm = e[c] / se;
        total += loss_list[c] * (1.f + wp * sm);
    }
    out[0] = total / (count * (1.f + WPC_C));
}

// ---------------------------------------------------------------------------
extern "C" void kernel_launch(void* const* d_in, const int* in_sizes, int n_in,
                              void* d_out, int out_size, void* d_ws, size_t ws_size,
                              hipStream_t stream) {
    const float* pred    = (const float*)d_in[0];
    const int*   tgt     = (const int*)d_in[1];
    const float* f1_list = (const float*)d_in[2];
    float* out = (float*)d_out;
    float* acc = (float*)d_ws;

    hipMemsetAsync(acc, 0, 3 * NC * sizeof(float), stream);
    al_reduce<<<dim3(1024), dim3(256), 0, stream>>>(pred, tgt, acc);
    al_finalize<<<dim3(1), dim3(64), 0, stream>>>(acc, f1_list, out);
}